// Round 21
// baseline (81.317 us; speedup 1.0000x reference)
//
#include <hip/hip_runtime.h>
#include <math.h>

#define B_    4
#define CIN_  64
#define COUT_ 64
#define H_    128
#define W_    160
#define HW_   (H_*W_)
#define NPIX_ (B_*HW_)      // 81920
#define XC_   72            // xsh channel stride: x(64) + sim(8), fp16
#define EPS_  1e-8f
#define NCH_  21            // cm K-chunks: ceil(648/32)
#define NLT_  5             // dcn W taps staged in LDS (0..4); 5..8 from L2

typedef float     f4    __attribute__((ext_vector_type(4)));
typedef float     f32x4 __attribute__((ext_vector_type(4)));
typedef _Float16  h8    __attribute__((ext_vector_type(8)));
typedef _Float16  h4    __attribute__((ext_vector_type(4)));

// ---------------------------------------------------------------------------
// prep:
//  wlin[k][j][s][lane][8] fp16 (9*4096): dcn W-fragments pre-linearized.
//  cwL[CH][s][lane][8] fp16 (21*1024): cm W-fragments, same linearization.
// ---------------------------------------------------------------------------
__global__ __launch_bounds__(256) void prep_kernel(const float* __restrict__ wt,
                                                   const float* __restrict__ cmw,
                                                   _Float16* __restrict__ wlin,
                                                   _Float16* __restrict__ cwL)
{
    int i = blockIdx.x * 256 + threadIdx.x;
    if (i < 9*4096) {
        int k = i >> 12, r = i & 4095;
        int j = r >> 10, s = (r >> 9) & 1, lane = (r >> 3) & 63, e = i & 7;
        int o = j*16 + (lane & 15);
        int c = s*32 + ((lane >> 4) << 3) + e;
        wlin[i] = (_Float16)wt[(o*64 + c)*9 + k];
    }
    int jj = i - 9*4096;
    if (jj >= 0 && jj < NCH_*1024) {
        int CH = jj >> 10, s = (jj >> 9) & 1, lane = (jj >> 3) & 63, e = jj & 7;
        int o  = s*16 + (lane & 15);
        int kk = ((lane >> 4) << 3) + e;
        int k  = CH*32 + kk;
        _Float16 v = (_Float16)0.f;
        if (o < 27 && k < 648) {
            int tap = k / 72, ch = k - (k/72)*72;
            v = (_Float16)cmw[((size_t)o*72 + ch)*9 + tap];
        }
        cwL[jj] = v;
    }
}

// ---------------------------------------------------------------------------
// xpose: NCHW f32 x -> fp16 NHWC xsh[px][0..63] (ch 64..71 filled by sim).
// ---------------------------------------------------------------------------
__global__ __launch_bounds__(128) void xpose_kernel(const float* __restrict__ x,
                                                    _Float16* __restrict__ xsh)
{
    __shared__ float l[128][65];
    const int t = threadIdx.x;
    const int px0 = blockIdx.x * 128;
    const int b = px0 / HW_, p0 = px0 % HW_;
    for (int c = 0; c < 64; c++)
        l[t][c] = x[((size_t)(b*64 + c))*HW_ + p0 + t];
    __syncthreads();
#pragma unroll
    for (int rep = 0; rep < 16; rep++) {
        int pxl = (t >> 4) + rep*8;
        int c4  = (t & 15) * 4;
        h4 v = { (_Float16)l[pxl][c4],   (_Float16)l[pxl][c4+1],
                 (_Float16)l[pxl][c4+2], (_Float16)l[pxl][c4+3] };
        *reinterpret_cast<h4*>(&xsh[(size_t)(px0+pxl)*XC_ + c4]) = v;
    }
}

// ---------------------------------------------------------------------------
// sim: 4 threads/pixel (16-ch quarters), 2-level shfl_xor combine.
// 256-thread blocks, 64 px each, grid 1280. Writes xsh[px][64..71].
// ---------------------------------------------------------------------------
__global__ __launch_bounds__(256, 4) void sim_kernel(_Float16* __restrict__ xsh)
{
    const int t = threadIdx.x;
    const int wg = blockIdx.x;
    const int sw = (wg & 7) * 160 + (wg >> 3);              // XCD-contiguous
    const int px = sw * 64 + (t >> 2);
    const int q = t & 3;
    const int w = px % W_, hh = (px / W_) % H_, b = px / HW_;

    const _Float16* cen = xsh + (size_t)px * XC_ + q*16;
    float cv[16]; float ncc = 0.f;
#pragma unroll
    for (int s = 0; s < 2; s++) {
        h8 cb = *reinterpret_cast<const h8*>(cen + s*8);
#pragma unroll
        for (int j = 0; j < 8; j++) {
            float v = (float)cb[j];
            cv[s*8+j] = v;
            ncc = fmaf(v, v, ncc);
        }
    }

    const int kyA[8] = {-1,-1,-1, 0, 0, 1, 1, 1};
    const int kxA[8] = {-1, 0, 1,-1, 1,-1, 0, 1};
    float dot[8], nn[8];
#pragma unroll
    for (int n = 0; n < 8; n++) {
        int hn = hh + kyA[n], wn = w + kxA[n];
        bool v = (hn >= 0) & (hn < H_) & (wn >= 0) & (wn < W_);
        float msk = v ? 1.f : 0.f;
        const _Float16* nb = xsh + (size_t)(b*HW_ + min(max(hn,0),H_-1)*W_ + min(max(wn,0),W_-1))*XC_ + q*16;
        float d = 0.f, s2 = 0.f;
#pragma unroll
        for (int s = 0; s < 2; s++) {
            h8 qb = *reinterpret_cast<const h8*>(nb + s*8);
#pragma unroll
            for (int j = 0; j < 8; j++) {
                float vv = (float)qb[j] * msk;
                d  = fmaf(cv[s*8+j], vv, d);
                s2 = fmaf(vv, vv, s2);
            }
        }
        dot[n] = d; nn[n] = s2;
    }
    ncc += __shfl_xor(ncc, 1); ncc += __shfl_xor(ncc, 2);
    const float ncr = 1.f / fmaxf(sqrtf(ncc), EPS_);
    float res[8];
#pragma unroll
    for (int n = 0; n < 8; n++) {
        float dt = dot[n]; dt += __shfl_xor(dt, 1); dt += __shfl_xor(dt, 2);
        float s2 = nn[n];  s2 += __shfl_xor(s2, 1); s2 += __shfl_xor(s2, 2);
        res[n] = dt * ncr / fmaxf(sqrtf(s2), EPS_);
    }
    if (q < 2) {
        h4 r = { (_Float16)res[q*4],   (_Float16)res[q*4+1],
                 (_Float16)res[q*4+2], (_Float16)res[q*4+3] };
        *reinterpret_cast<h4*>(xsh + (size_t)px * XC_ + 64 + q*4) = r;
    }
}

// ---------------------------------------------------------------------------
// cmdcn: FUSED cm + dcn, fp16. Block = 64 px, 4 waves, grid 1280.
// HYBRID W placement: taps 0..4 staged in LDS at start (40KB; loads retire
// under cm), taps 5..8 read from L2 (wave-uniform branch). LDS total
// 47.4KB -> 3 blocks/CU (37.5% cap) vs R20's 72KB/25% cap: trades back
// ~55% of the L2 saving for +50% occupancy on a latency-bound kernel.
// ---------------------------------------------------------------------------
__global__ __launch_bounds__(256, 3) void cmdcn_kernel(const _Float16* __restrict__ xsh,
                                                       const _Float16* __restrict__ cwL,
                                                       const float* __restrict__ cmb,
                                                       const _Float16* __restrict__ wlin,
                                                       const float* __restrict__ bias,
                                                       float* __restrict__ out)
{
    __shared__ float om_l[64][29];                          // 7.4 KB
    __shared__ __align__(16) _Float16 WLds[NLT_*4096];      // 40 KB

    const int t  = threadIdx.x;
    const int wg = blockIdx.x;
    const int sw = (wg & 7) * 160 + (wg >> 3);              // XCD-contiguous
    const int px0 = sw * 64;
    const int lane = t & 63, wv = t >> 6;
    const int fr = lane & 15, fq = lane >> 4;

    // ---- stage W taps 0..4 to LDS (2560 chunks = 10 rounds x 256 thr) ----
#pragma unroll 2
    for (int r = 0; r < 10; r++) {
        int cb = r*256 + t;
        *reinterpret_cast<h8*>(&WLds[cb*8]) =
            *reinterpret_cast<const h8*>(wlin + cb*8);
    }

    const int pxs = px0 + wv*16 + fr;
    const int wsx = pxs % W_, hs = (pxs / W_) % H_, bs = pxs / HW_;
    const size_t xrow = (size_t)bs * HW_;

    // ================= phase 1: cm (2-deep ping-pong) =================
    {
        f32x4 acc[2];
        acc[0] = (f32x4){0.f,0.f,0.f,0.f};
        acc[1] = (f32x4){0.f,0.f,0.f,0.f};

#define CM_ISSUE_G(CH, G8, MSK) do {                                          \
    int k0_ = (CH)*32 + fq*8;                                                 \
    int tap_ = (k0_ * 911) >> 16;                                             \
    bool valid_ = (tap_ < 9);                                                 \
    tap_ = min(tap_, 8);                                                      \
    int ch_ = min(max(k0_ - tap_*72, 0), 64);                                 \
    int t3_ = (tap_ * 11) >> 5;                                               \
    int hy_ = hs + t3_ - 1, wx_ = wsx + (tap_ - t3_*3) - 1;                   \
    bool v_ = (hy_ >= 0) & (hy_ < H_) & (wx_ >= 0) & (wx_ < W_);              \
    MSK = v_ & valid_;                                                        \
    const _Float16* src_ = xsh + (size_t)(xrow + min(max(hy_,0),H_-1)*W_      \
                                          + min(max(wx_,0),W_-1))*XC_ + ch_;  \
    G8 = *reinterpret_cast<const h8*>(src_);                                  \
  } while(0)

#define CM_ISSUE_W(CH, WF) do {                                               \
    const _Float16* wp_ = cwL + (CH)*1024 + lane*8;                           \
    WF[0] = *reinterpret_cast<const h8*>(wp_);                                \
    WF[1] = *reinterpret_cast<const h8*>(wp_ + 512);                          \
  } while(0)

#define CM_MFMA(G8, MSK, WF) do {                                             \
    h8 zero8_ = {(_Float16)0.f,(_Float16)0.f,(_Float16)0.f,(_Float16)0.f,     \
                 (_Float16)0.f,(_Float16)0.f,(_Float16)0.f,(_Float16)0.f};    \
    h8 AF_ = (MSK) ? (G8) : zero8_;                                           \
    acc[0] = __builtin_amdgcn_mfma_f32_16x16x32_f16(AF_, WF[0], acc[0],0,0,0);\
    acc[1] = __builtin_amdgcn_mfma_f32_16x16x32_f16(AF_, WF[1], acc[1],0,0,0);\
  } while(0)

        h8 GAc, GBc; h8 WFA[2], WFB[2]; bool mskA, mskB;
        CM_ISSUE_G(0, GAc, mskA); CM_ISSUE_W(0, WFA);
        CM_ISSUE_G(1, GBc, mskB); CM_ISSUE_W(1, WFB);

#pragma unroll 1
        for (int cp = 0; cp < 10; cp++) {
            const int cce = cp*2;
            {   // even chunk cce (GA)
                h8 G = GAc; bool m = mskA; h8 W0 = WFA[0], W1 = WFA[1];
                if (cce + 2 < NCH_) { CM_ISSUE_G(cce+2, GAc, mskA); CM_ISSUE_W(cce+2, WFA); }
                h8 zero8_ = {(_Float16)0.f,(_Float16)0.f,(_Float16)0.f,(_Float16)0.f,
                             (_Float16)0.f,(_Float16)0.f,(_Float16)0.f,(_Float16)0.f};
                h8 AF_ = m ? G : zero8_;
                acc[0] = __builtin_amdgcn_mfma_f32_16x16x32_f16(AF_, W0, acc[0],0,0,0);
                acc[1] = __builtin_amdgcn_mfma_f32_16x16x32_f16(AF_, W1, acc[1],0,0,0);
            }
            {   // odd chunk cce+1 (GB)
                h8 G = GBc; bool m = mskB; h8 W0 = WFB[0], W1 = WFB[1];
                if (cce + 3 < NCH_) { CM_ISSUE_G(cce+3, GBc, mskB); CM_ISSUE_W(cce+3, WFB); }
                h8 zero8_ = {(_Float16)0.f,(_Float16)0.f,(_Float16)0.f,(_Float16)0.f,
                             (_Float16)0.f,(_Float16)0.f,(_Float16)0.f,(_Float16)0.f};
                h8 AF_ = m ? G : zero8_;
                acc[0] = __builtin_amdgcn_mfma_f32_16x16x32_f16(AF_, W0, acc[0],0,0,0);
                acc[1] = __builtin_amdgcn_mfma_f32_16x16x32_f16(AF_, W1, acc[1],0,0,0);
            }
        }
        CM_MFMA(GAc, mskA, WFA);                            // tail chunk 20

        // epilogue -> LDS: row px = wv*16 + fq*4 + r, col o = j*16 + fr
        const int rl = wv*16 + fq*4;
#pragma unroll
        for (int j = 0; j < 2; j++) {
            int o = j*16 + fr;
            if (o < 27) {
                float bv = cmb[o];
#pragma unroll
                for (int r = 0; r < 4; r++)
                    om_l[rl + r][o] = acc[j][r] + bv;
            }
        }
    }
    __syncthreads();                                        // covers W staging too

    // ================= phase 2: dcn (G ping-pong; W hybrid LDS/L2) ========
    const int ce = fq * 8;
    const int rp = wv*16 + fr;                              // this lane's px row
    const int lb = lane*8;

    f32x4 acc[4];
#pragma unroll
    for (int j = 0; j < 4; j++) acc[j] = (f32x4){0.f,0.f,0.f,0.f};

#define DCN_META(KK, W00, W01, W10, W11, P0, P1, P2, P3) do {                 \
    float dy_ = om_l[rp][2*(KK)], dx_ = om_l[rp][2*(KK)+1];                   \
    float mz_ = om_l[rp][18+(KK)];                                            \
    float m_  = 1.f / (1.f + __expf(-mz_));                                   \
    float py_ = (float)(hs + (KK)/3 - 1) + dy_;                               \
    float px_ = (float)(wsx + (KK)%3 - 1) + dx_;                              \
    float y0f_ = floorf(py_), x0f_ = floorf(px_);                             \
    int   y0_ = (int)y0f_,   x0_ = (int)x0f_;                                 \
    float wy_ = py_ - y0f_,  wx_ = px_ - x0f_;                                \
    bool vy0_ = (y0_ >= 0)  & (y0_ < H_);                                     \
    bool vy1_ = (y0_ >= -1) & (y0_ < H_ - 1);                                 \
    bool vx0_ = (x0_ >= 0)  & (x0_ < W_);                                     \
    bool vx1_ = (x0_ >= -1) & (x0_ < W_ - 1);                                 \
    W00 = (1.f-wy_)*(1.f-wx_)*m_*((vy0_&vx0_)?1.f:0.f);                       \
    W01 = (1.f-wy_)*wx_      *m_*((vy0_&vx1_)?1.f:0.f);                       \
    W10 = wy_*(1.f-wx_)      *m_*((vy1_&vx0_)?1.f:0.f);                       \
    W11 = wy_*wx_            *m_*((vy1_&vx1_)?1.f:0.f);                       \
    int y0c_ = min(max(y0_,   0), H_-1), y1c_ = min(max(y0_+1, 0), H_-1);     \
    int x0c_ = min(max(x0_,   0), W_-1), x1c_ = min(max(x0_+1, 0), W_-1);     \
    P0 = xsh + (size_t)(xrow + y0c_*W_ + x0c_)*XC_ + ce;                      \
    P1 = xsh + (size_t)(xrow + y0c_*W_ + x1c_)*XC_ + ce;                      \
    P2 = xsh + (size_t)(xrow + y1c_*W_ + x0c_)*XC_ + ce;                      \
    P3 = xsh + (size_t)(xrow + y1c_*W_ + x1c_)*XC_ + ce;                      \
  } while(0)

#define DCN_GATHER(G, P0, P1, P2, P3) do {                                    \
    G[0] = *reinterpret_cast<const h8*>(P0);                                  \
    G[1] = *reinterpret_cast<const h8*>(P0 + 32);                             \
    G[2] = *reinterpret_cast<const h8*>(P1);                                  \
    G[3] = *reinterpret_cast<const h8*>(P1 + 32);                             \
    G[4] = *reinterpret_cast<const h8*>(P2);                                  \
    G[5] = *reinterpret_cast<const h8*>(P2 + 32);                             \
    G[6] = *reinterpret_cast<const h8*>(P3);                                  \
    G[7] = *reinterpret_cast<const h8*>(P3 + 32);                             \
  } while(0)

#define DCN_WREAD(KK, WF) do {                                                \
    const _Float16* wp_ = &WLds[(KK)*4096 + lb];                              \
    WF[0] = *reinterpret_cast<const h8*>(wp_);                                \
    WF[1] = *reinterpret_cast<const h8*>(wp_ + 512);                          \
    WF[2] = *reinterpret_cast<const h8*>(wp_ + 1024);                         \
    WF[3] = *reinterpret_cast<const h8*>(wp_ + 1536);                         \
    WF[4] = *reinterpret_cast<const h8*>(wp_ + 2048);                         \
    WF[5] = *reinterpret_cast<const h8*>(wp_ + 2560);                         \
    WF[6] = *reinterpret_cast<const h8*>(wp_ + 3072);                         \
    WF[7] = *reinterpret_cast<const h8*>(wp_ + 3584);                         \
  } while(0)

#define DCN_WLOAD(KK, WF) do {                                                \
    const _Float16* wp_ = wlin + (KK)*4096 + lb;                              \
    WF[0] = *reinterpret_cast<const h8*>(wp_);                                \
    WF[1] = *reinterpret_cast<const h8*>(wp_ + 512);                          \
    WF[2] = *reinterpret_cast<const h8*>(wp_ + 1024);                         \
    WF[3] = *reinterpret_cast<const h8*>(wp_ + 1536);                         \
    WF[4] = *reinterpret_cast<const h8*>(wp_ + 2048);                         \
    WF[5] = *reinterpret_cast<const h8*>(wp_ + 2560);                         \
    WF[6] = *reinterpret_cast<const h8*>(wp_ + 3072);                         \
    WF[7] = *reinterpret_cast<const h8*>(wp_ + 3584);                         \
  } while(0)

#define DCN_WANY(KK, WF) do {                                                 \
    if ((KK) < NLT_) DCN_WREAD(KK, WF); else DCN_WLOAD(KK, WF);               \
  } while(0)

#define DCN_COMBINE(G, W00, W01, W10, W11, AA, AB) do {                       \
    _Float16 h00 = (_Float16)(W00), h01 = (_Float16)(W01);                    \
    _Float16 h10 = (_Float16)(W10), h11 = (_Float16)(W11);                    \
    h8 v00 = {h00,h00,h00,h00,h00,h00,h00,h00};                               \
    h8 v01 = {h01,h01,h01,h01,h01,h01,h01,h01};                               \
    h8 v10 = {h10,h10,h10,h10,h10,h10,h10,h10};                               \
    h8 v11 = {h11,h11,h11,h11,h11,h11,h11,h11};                               \
    AA = v00*G[0] + v01*G[2] + v10*G[4] + v11*G[6];                           \
    AB = v00*G[1] + v01*G[3] + v10*G[5] + v11*G[7];                           \
  } while(0)

#define DCN_MFMA(WF, AA, AB) do {                                             \
    acc[0] = __builtin_amdgcn_mfma_f32_16x16x32_f16(AA, WF[0], acc[0],0,0,0); \
    acc[0] = __builtin_amdgcn_mfma_f32_16x16x32_f16(AB, WF[1], acc[0],0,0,0); \
    acc[1] = __builtin_amdgcn_mfma_f32_16x16x32_f16(AA, WF[2], acc[1],0,0,0); \
    acc[1] = __builtin_amdgcn_mfma_f32_16x16x32_f16(AB, WF[3], acc[1],0,0,0); \
    acc[2] = __builtin_amdgcn_mfma_f32_16x16x32_f16(AA, WF[4], acc[2],0,0,0); \
    acc[2] = __builtin_amdgcn_mfma_f32_16x16x32_f16(AB, WF[5], acc[2],0,0,0); \
    acc[3] = __builtin_amdgcn_mfma_f32_16x16x32_f16(AA, WF[6], acc[3],0,0,0); \
    acc[3] = __builtin_amdgcn_mfma_f32_16x16x32_f16(AB, WF[7], acc[3],0,0,0); \
  } while(0)

    // ---- prologue: GA(0) in flight; meta(1) ready ----
    float wA00, wA01, wA10, wA11; const _Float16 *pA0, *pA1, *pA2, *pA3;
    float wB00, wB01, wB10, wB11; const _Float16 *pB0, *pB1, *pB2, *pB3;
    h8 GA[8], GB[8];

    DCN_META(0, wA00,wA01,wA10,wA11, pA0,pA1,pA2,pA3);
    DCN_GATHER(GA, pA0,pA1,pA2,pA3);
    DCN_META(1, wB00,wB01,wB10,wB11, pB0,pB1,pB2,pB3);

#pragma unroll 1
    for (int kp = 0; kp < 4; kp++) {
        const int ke = kp*2;
        // ---- tap ke (even): GA holds data ----
        DCN_GATHER(GB, pB0,pB1,pB2,pB3);                // tap ke+1 in flight
        h8 WE[8]; DCN_WANY(ke, WE);
        float nA00,nA01,nA10,nA11; const _Float16 *qA0,*qA1,*qA2,*qA3;
        DCN_META(ke+2, nA00,nA01,nA10,nA11, qA0,qA1,qA2,qA3);   // ke+2 <= 8
        h8 aA, aB; DCN_COMBINE(GA, wA00,wA01,wA10,wA11, aA, aB);
        DCN_MFMA(WE, aA, aB);
        wA00=nA00; wA01=nA01; wA10=nA10; wA11=nA11;
        pA0=qA0; pA1=qA1; pA2=qA2; pA3=qA3;
        DCN_GATHER(GA, pA0,pA1,pA2,pA3);                // tap ke+2 in flight

        // ---- tap ke+1 (odd): GB holds data ----
        h8 WO[8]; DCN_WANY(ke+1, WO);
        float nB00,nB01,nB10,nB11; const _Float16 *qB0,*qB1,*qB2,*qB3;
        if (kp < 3) {
            DCN_META(ke+3, nB00,nB01,nB10,nB11, qB0,qB1,qB2,qB3);
        } else {
            nB00=wB00; nB01=wB01; nB10=wB10; nB11=wB11;
            qB0=pB0; qB1=pB1; qB2=pB2; qB3=pB3;
        }
        h8 cA, cB; DCN_COMBINE(GB, wB00,wB01,wB10,wB11, cA, cB);
        DCN_MFMA(WO, cA, cB);
        wB00=nB00; wB01=nB01; wB10=nB10; wB11=nB11;
        pB0=qB0; pB1=qB1; pB2=qB2; pB3=qB3;
    }

    // ---- tap 8 (in GA / wA), W from L2 ----
    {
        h8 WE[8]; DCN_WLOAD(8, WE);
        h8 aA, aB; DCN_COMBINE(GA, wA00,wA01,wA10,wA11, aA, aB);
        DCN_MFMA(WE, aA, aB);
    }

    // ---- epilogue: D row px = wv*16 + fq*4 + reg, col o = j*16 + fr ----
    const int bo = px0 / HW_, po = px0 % HW_;
#pragma unroll
    for (int j = 0; j < 4; j++) {
        int o = j*16 + fr;
        float bv = bias[o];
        f4 r = { acc[j][0] + bv, acc[j][1] + bv, acc[j][2] + bv, acc[j][3] + bv };
        *reinterpret_cast<f4*>(&out[((size_t)(bo*64 + o))*HW_ + po + wv*16 + fq*4]) = r;
    }
}

// ---------------------------------------------------------------------------
extern "C" void kernel_launch(void* const* d_in, const int* in_sizes, int n_in,
                              void* d_out, int out_size, void* d_ws, size_t ws_size,
                              hipStream_t stream)
{
    const float* x   = (const float*)d_in[0];
    const float* wt  = (const float*)d_in[1];
    const float* bs  = (const float*)d_in[2];
    const float* cmw = (const float*)d_in[3];
    const float* cmb = (const float*)d_in[4];
    float* out = (float*)d_out;

    _Float16* xsh  = (_Float16*)d_ws;                       // NPIX_*72 fp16
    _Float16* wlin = xsh + (size_t)NPIX_ * XC_;             // 9*4096 fp16
    _Float16* cwL  = wlin + 9*4096;                         // 21*1024 fp16

    prep_kernel <<<228, 256, 0, stream>>>(wt, cmw, wlin, cwL);
    xpose_kernel<<<NPIX_/128, 128, 0, stream>>>(x, xsh);
    sim_kernel  <<<NPIX_/64,  256, 0, stream>>>(xsh);
    cmdcn_kernel<<<NPIX_/64,  256, 0, stream>>>(xsh, cwL, cmb, wlin, bs, out);
}

// Round 22
// 73.773 us; speedup vs baseline: 1.1023x; 1.1023x over previous
//
#include <hip/hip_runtime.h>
#include <math.h>

#define B_    4
#define CIN_  64
#define COUT_ 64
#define H_    128
#define W_    160
#define HW_   (H_*W_)
#define NPIX_ (B_*HW_)      // 81920
#define XC_   72            // xsh channel stride: x(64) + sim(8), fp16
#define EPS_  1e-8f
#define NCH_  21            // cm K-chunks: ceil(648/32)

typedef float     f4    __attribute__((ext_vector_type(4)));
typedef float     f32x4 __attribute__((ext_vector_type(4)));
typedef _Float16  h8    __attribute__((ext_vector_type(8)));
typedef _Float16  h4    __attribute__((ext_vector_type(4)));

// ---------------------------------------------------------------------------
// prep:
//  wlin[k][j][s][lane][8] fp16 (9*4096): dcn W-fragments pre-linearized.
//  cwL[CH][s][lane][8] fp16 (21*1024): cm W-fragments, same linearization.
// ---------------------------------------------------------------------------
__global__ __launch_bounds__(256) void prep_kernel(const float* __restrict__ wt,
                                                   const float* __restrict__ cmw,
                                                   _Float16* __restrict__ wlin,
                                                   _Float16* __restrict__ cwL)
{
    int i = blockIdx.x * 256 + threadIdx.x;
    if (i < 9*4096) {
        int k = i >> 12, r = i & 4095;
        int j = r >> 10, s = (r >> 9) & 1, lane = (r >> 3) & 63, e = i & 7;
        int o = j*16 + (lane & 15);
        int c = s*32 + ((lane >> 4) << 3) + e;
        wlin[i] = (_Float16)wt[(o*64 + c)*9 + k];
    }
    int jj = i - 9*4096;
    if (jj >= 0 && jj < NCH_*1024) {
        int CH = jj >> 10, s = (jj >> 9) & 1, lane = (jj >> 3) & 63, e = jj & 7;
        int o  = s*16 + (lane & 15);
        int kk = ((lane >> 4) << 3) + e;
        int k  = CH*32 + kk;
        _Float16 v = (_Float16)0.f;
        if (o < 27 && k < 648) {
            int tap = k / 72, ch = k - (k/72)*72;
            v = (_Float16)cmw[((size_t)o*72 + ch)*9 + tap];
        }
        cwL[jj] = v;
    }
}

// ---------------------------------------------------------------------------
// xpose: NCHW f32 x -> fp16 NHWC xsh[px][0..63] (ch 64..71 filled by sim).
// ---------------------------------------------------------------------------
__global__ __launch_bounds__(128) void xpose_kernel(const float* __restrict__ x,
                                                    _Float16* __restrict__ xsh)
{
    __shared__ float l[128][65];
    const int t = threadIdx.x;
    const int px0 = blockIdx.x * 128;
    const int b = px0 / HW_, p0 = px0 % HW_;
    for (int c = 0; c < 64; c++)
        l[t][c] = x[((size_t)(b*64 + c))*HW_ + p0 + t];
    __syncthreads();
#pragma unroll
    for (int rep = 0; rep < 16; rep++) {
        int pxl = (t >> 4) + rep*8;
        int c4  = (t & 15) * 4;
        h4 v = { (_Float16)l[pxl][c4],   (_Float16)l[pxl][c4+1],
                 (_Float16)l[pxl][c4+2], (_Float16)l[pxl][c4+3] };
        *reinterpret_cast<h4*>(&xsh[(size_t)(px0+pxl)*XC_ + c4]) = v;
    }
}

// ---------------------------------------------------------------------------
// sim: 4 threads/pixel (16-ch quarters), 2-level shfl_xor combine.
// 256-thread blocks, 64 px each, grid 1280. Writes xsh[px][64..71].
// ---------------------------------------------------------------------------
__global__ __launch_bounds__(256, 4) void sim_kernel(_Float16* __restrict__ xsh)
{
    const int t = threadIdx.x;
    const int wg = blockIdx.x;
    const int sw = (wg & 7) * 160 + (wg >> 3);              // XCD-contiguous
    const int px = sw * 64 + (t >> 2);
    const int q = t & 3;
    const int w = px % W_, hh = (px / W_) % H_, b = px / HW_;

    const _Float16* cen = xsh + (size_t)px * XC_ + q*16;
    float cv[16]; float ncc = 0.f;
#pragma unroll
    for (int s = 0; s < 2; s++) {
        h8 cb = *reinterpret_cast<const h8*>(cen + s*8);
#pragma unroll
        for (int j = 0; j < 8; j++) {
            float v = (float)cb[j];
            cv[s*8+j] = v;
            ncc = fmaf(v, v, ncc);
        }
    }

    const int kyA[8] = {-1,-1,-1, 0, 0, 1, 1, 1};
    const int kxA[8] = {-1, 0, 1,-1, 1,-1, 0, 1};
    float dot[8], nn[8];
#pragma unroll
    for (int n = 0; n < 8; n++) {
        int hn = hh + kyA[n], wn = w + kxA[n];
        bool v = (hn >= 0) & (hn < H_) & (wn >= 0) & (wn < W_);
        float msk = v ? 1.f : 0.f;
        const _Float16* nb = xsh + (size_t)(b*HW_ + min(max(hn,0),H_-1)*W_ + min(max(wn,0),W_-1))*XC_ + q*16;
        float d = 0.f, s2 = 0.f;
#pragma unroll
        for (int s = 0; s < 2; s++) {
            h8 qb = *reinterpret_cast<const h8*>(nb + s*8);
#pragma unroll
            for (int j = 0; j < 8; j++) {
                float vv = (float)qb[j] * msk;
                d  = fmaf(cv[s*8+j], vv, d);
                s2 = fmaf(vv, vv, s2);
            }
        }
        dot[n] = d; nn[n] = s2;
    }
    ncc += __shfl_xor(ncc, 1); ncc += __shfl_xor(ncc, 2);
    const float ncr = 1.f / fmaxf(sqrtf(ncc), EPS_);
    float res[8];
#pragma unroll
    for (int n = 0; n < 8; n++) {
        float dt = dot[n]; dt += __shfl_xor(dt, 1); dt += __shfl_xor(dt, 2);
        float s2 = nn[n];  s2 += __shfl_xor(s2, 1); s2 += __shfl_xor(s2, 2);
        res[n] = dt * ncr / fmaxf(sqrtf(s2), EPS_);
    }
    if (q < 2) {
        h4 r = { (_Float16)res[q*4],   (_Float16)res[q*4+1],
                 (_Float16)res[q*4+2], (_Float16)res[q*4+3] };
        *reinterpret_cast<h4*>(xsh + (size_t)px * XC_ + 64 + q*4) = r;
    }
}

// ---------------------------------------------------------------------------
// cmdcn: FUSED cm + dcn, fp16. Block = 64 px, 4 waves, grid 1280.
// R20 shape (measured best: 48.4us, FETCH 6.45MB): all 9 dcn W taps (72KB)
// staged into LDS at kernel start; dcn tap loop has no W VMEM. NEW in R22:
// s_setprio(1) around MFMA clusters (T5) — no in-loop barriers means waves
// run at diverse phases, the regime where setprio measured +4-7% (m191).
// R21's hybrid LDS/L2 W (runtime branch) regressed: L2 traffic is the
// lever here, occupancy is not (R20 vs R21 A/B).
// ---------------------------------------------------------------------------
__global__ __launch_bounds__(256, 2) void cmdcn_kernel(const _Float16* __restrict__ xsh,
                                                       const _Float16* __restrict__ cwL,
                                                       const float* __restrict__ cmb,
                                                       const _Float16* __restrict__ wlin,
                                                       const float* __restrict__ bias,
                                                       float* __restrict__ out)
{
    __shared__ float om_l[64][29];                          // 7.4 KB
    __shared__ __align__(16) _Float16 WLds[9*4096];         // 72 KB

    const int t  = threadIdx.x;
    const int wg = blockIdx.x;
    const int sw = (wg & 7) * 160 + (wg >> 3);              // XCD-contiguous
    const int px0 = sw * 64;
    const int lane = t & 63, wv = t >> 6;
    const int fr = lane & 15, fq = lane >> 4;

    // ---- stage all 9 W taps to LDS (4608 chunks = 18 rounds x 256 thr) ----
#pragma unroll 3
    for (int r = 0; r < 18; r++) {
        int cb = r*256 + t;
        *reinterpret_cast<h8*>(&WLds[cb*8]) =
            *reinterpret_cast<const h8*>(wlin + cb*8);
    }

    const int pxs = px0 + wv*16 + fr;
    const int wsx = pxs % W_, hs = (pxs / W_) % H_, bs = pxs / HW_;
    const size_t xrow = (size_t)bs * HW_;

    // ================= phase 1: cm (2-deep ping-pong) =================
    {
        f32x4 acc[2];
        acc[0] = (f32x4){0.f,0.f,0.f,0.f};
        acc[1] = (f32x4){0.f,0.f,0.f,0.f};

#define CM_ISSUE_G(CH, G8, MSK) do {                                          \
    int k0_ = (CH)*32 + fq*8;                                                 \
    int tap_ = (k0_ * 911) >> 16;                                             \
    bool valid_ = (tap_ < 9);                                                 \
    tap_ = min(tap_, 8);                                                      \
    int ch_ = min(max(k0_ - tap_*72, 0), 64);                                 \
    int t3_ = (tap_ * 11) >> 5;                                               \
    int hy_ = hs + t3_ - 1, wx_ = wsx + (tap_ - t3_*3) - 1;                   \
    bool v_ = (hy_ >= 0) & (hy_ < H_) & (wx_ >= 0) & (wx_ < W_);              \
    MSK = v_ & valid_;                                                        \
    const _Float16* src_ = xsh + (size_t)(xrow + min(max(hy_,0),H_-1)*W_      \
                                          + min(max(wx_,0),W_-1))*XC_ + ch_;  \
    G8 = *reinterpret_cast<const h8*>(src_);                                  \
  } while(0)

#define CM_ISSUE_W(CH, WF) do {                                               \
    const _Float16* wp_ = cwL + (CH)*1024 + lane*8;                           \
    WF[0] = *reinterpret_cast<const h8*>(wp_);                                \
    WF[1] = *reinterpret_cast<const h8*>(wp_ + 512);                          \
  } while(0)

#define CM_MFMA(G8, MSK, WF) do {                                             \
    h8 zero8_ = {(_Float16)0.f,(_Float16)0.f,(_Float16)0.f,(_Float16)0.f,     \
                 (_Float16)0.f,(_Float16)0.f,(_Float16)0.f,(_Float16)0.f};    \
    h8 AF_ = (MSK) ? (G8) : zero8_;                                           \
    __builtin_amdgcn_s_setprio(1);                                            \
    acc[0] = __builtin_amdgcn_mfma_f32_16x16x32_f16(AF_, WF[0], acc[0],0,0,0);\
    acc[1] = __builtin_amdgcn_mfma_f32_16x16x32_f16(AF_, WF[1], acc[1],0,0,0);\
    __builtin_amdgcn_s_setprio(0);                                            \
  } while(0)

        h8 GAc, GBc; h8 WFA[2], WFB[2]; bool mskA, mskB;
        CM_ISSUE_G(0, GAc, mskA); CM_ISSUE_W(0, WFA);
        CM_ISSUE_G(1, GBc, mskB); CM_ISSUE_W(1, WFB);

#pragma unroll 1
        for (int cp = 0; cp < 10; cp++) {
            const int cce = cp*2;
            {   // even chunk cce (GA)
                h8 G = GAc; bool m = mskA; h8 W0 = WFA[0], W1 = WFA[1];
                if (cce + 2 < NCH_) { CM_ISSUE_G(cce+2, GAc, mskA); CM_ISSUE_W(cce+2, WFA); }
                h8 zero8_ = {(_Float16)0.f,(_Float16)0.f,(_Float16)0.f,(_Float16)0.f,
                             (_Float16)0.f,(_Float16)0.f,(_Float16)0.f,(_Float16)0.f};
                h8 AF_ = m ? G : zero8_;
                __builtin_amdgcn_s_setprio(1);
                acc[0] = __builtin_amdgcn_mfma_f32_16x16x32_f16(AF_, W0, acc[0],0,0,0);
                acc[1] = __builtin_amdgcn_mfma_f32_16x16x32_f16(AF_, W1, acc[1],0,0,0);
                __builtin_amdgcn_s_setprio(0);
            }
            {   // odd chunk cce+1 (GB)
                h8 G = GBc; bool m = mskB; h8 W0 = WFB[0], W1 = WFB[1];
                if (cce + 3 < NCH_) { CM_ISSUE_G(cce+3, GBc, mskB); CM_ISSUE_W(cce+3, WFB); }
                h8 zero8_ = {(_Float16)0.f,(_Float16)0.f,(_Float16)0.f,(_Float16)0.f,
                             (_Float16)0.f,(_Float16)0.f,(_Float16)0.f,(_Float16)0.f};
                h8 AF_ = m ? G : zero8_;
                __builtin_amdgcn_s_setprio(1);
                acc[0] = __builtin_amdgcn_mfma_f32_16x16x32_f16(AF_, W0, acc[0],0,0,0);
                acc[1] = __builtin_amdgcn_mfma_f32_16x16x32_f16(AF_, W1, acc[1],0,0,0);
                __builtin_amdgcn_s_setprio(0);
            }
        }
        CM_MFMA(GAc, mskA, WFA);                            // tail chunk 20

        // epilogue -> LDS: row px = wv*16 + fq*4 + r, col o = j*16 + fr
        const int rl = wv*16 + fq*4;
#pragma unroll
        for (int j = 0; j < 2; j++) {
            int o = j*16 + fr;
            if (o < 27) {
                float bv = cmb[o];
#pragma unroll
                for (int r = 0; r < 4; r++)
                    om_l[rl + r][o] = acc[j][r] + bv;
            }
        }
    }
    __syncthreads();                                        // covers W staging too

    // ================= phase 2: dcn (G ping-pong; W from LDS) =============
    const int ce = fq * 8;
    const int rp = wv*16 + fr;                              // this lane's px row
    const int lb = lane*8;

    f32x4 acc[4];
#pragma unroll
    for (int j = 0; j < 4; j++) acc[j] = (f32x4){0.f,0.f,0.f,0.f};

#define DCN_META(KK, W00, W01, W10, W11, P0, P1, P2, P3) do {                 \
    float dy_ = om_l[rp][2*(KK)], dx_ = om_l[rp][2*(KK)+1];                   \
    float mz_ = om_l[rp][18+(KK)];                                            \
    float m_  = 1.f / (1.f + __expf(-mz_));                                   \
    float py_ = (float)(hs + (KK)/3 - 1) + dy_;                               \
    float px_ = (float)(wsx + (KK)%3 - 1) + dx_;                              \
    float y0f_ = floorf(py_), x0f_ = floorf(px_);                             \
    int   y0_ = (int)y0f_,   x0_ = (int)x0f_;                                 \
    float wy_ = py_ - y0f_,  wx_ = px_ - x0f_;                                \
    bool vy0_ = (y0_ >= 0)  & (y0_ < H_);                                     \
    bool vy1_ = (y0_ >= -1) & (y0_ < H_ - 1);                                 \
    bool vx0_ = (x0_ >= 0)  & (x0_ < W_);                                     \
    bool vx1_ = (x0_ >= -1) & (x0_ < W_ - 1);                                 \
    W00 = (1.f-wy_)*(1.f-wx_)*m_*((vy0_&vx0_)?1.f:0.f);                       \
    W01 = (1.f-wy_)*wx_      *m_*((vy0_&vx1_)?1.f:0.f);                       \
    W10 = wy_*(1.f-wx_)      *m_*((vy1_&vx0_)?1.f:0.f);                       \
    W11 = wy_*wx_            *m_*((vy1_&vx1_)?1.f:0.f);                       \
    int y0c_ = min(max(y0_,   0), H_-1), y1c_ = min(max(y0_+1, 0), H_-1);     \
    int x0c_ = min(max(x0_,   0), W_-1), x1c_ = min(max(x0_+1, 0), W_-1);     \
    P0 = xsh + (size_t)(xrow + y0c_*W_ + x0c_)*XC_ + ce;                      \
    P1 = xsh + (size_t)(xrow + y0c_*W_ + x1c_)*XC_ + ce;                      \
    P2 = xsh + (size_t)(xrow + y1c_*W_ + x0c_)*XC_ + ce;                      \
    P3 = xsh + (size_t)(xrow + y1c_*W_ + x1c_)*XC_ + ce;                      \
  } while(0)

#define DCN_GATHER(G, P0, P1, P2, P3) do {                                    \
    G[0] = *reinterpret_cast<const h8*>(P0);                                  \
    G[1] = *reinterpret_cast<const h8*>(P0 + 32);                             \
    G[2] = *reinterpret_cast<const h8*>(P1);                                  \
    G[3] = *reinterpret_cast<const h8*>(P1 + 32);                             \
    G[4] = *reinterpret_cast<const h8*>(P2);                                  \
    G[5] = *reinterpret_cast<const h8*>(P2 + 32);                             \
    G[6] = *reinterpret_cast<const h8*>(P3);                                  \
    G[7] = *reinterpret_cast<const h8*>(P3 + 32);                             \
  } while(0)

#define DCN_WREAD(KK, WF) do {                                                \
    const _Float16* wp_ = &WLds[(KK)*4096 + lb];                              \
    WF[0] = *reinterpret_cast<const h8*>(wp_);                                \
    WF[1] = *reinterpret_cast<const h8*>(wp_ + 512);                          \
    WF[2] = *reinterpret_cast<const h8*>(wp_ + 1024);                         \
    WF[3] = *reinterpret_cast<const h8*>(wp_ + 1536);                         \
    WF[4] = *reinterpret_cast<const h8*>(wp_ + 2048);                         \
    WF[5] = *reinterpret_cast<const h8*>(wp_ + 2560);                         \
    WF[6] = *reinterpret_cast<const h8*>(wp_ + 3072);                         \
    WF[7] = *reinterpret_cast<const h8*>(wp_ + 3584);                         \
  } while(0)

#define DCN_COMBINE(G, W00, W01, W10, W11, AA, AB) do {                       \
    _Float16 h00 = (_Float16)(W00), h01 = (_Float16)(W01);                    \
    _Float16 h10 = (_Float16)(W10), h11 = (_Float16)(W11);                    \
    h8 v00 = {h00,h00,h00,h00,h00,h00,h00,h00};                               \
    h8 v01 = {h01,h01,h01,h01,h01,h01,h01,h01};                               \
    h8 v10 = {h10,h10,h10,h10,h10,h10,h10,h10};                               \
    h8 v11 = {h11,h11,h11,h11,h11,h11,h11,h11};                               \
    AA = v00*G[0] + v01*G[2] + v10*G[4] + v11*G[6];                           \
    AB = v00*G[1] + v01*G[3] + v10*G[5] + v11*G[7];                           \
  } while(0)

#define DCN_MFMA(WF, AA, AB) do {                                             \
    __builtin_amdgcn_s_setprio(1);                                            \
    acc[0] = __builtin_amdgcn_mfma_f32_16x16x32_f16(AA, WF[0], acc[0],0,0,0); \
    acc[0] = __builtin_amdgcn_mfma_f32_16x16x32_f16(AB, WF[1], acc[0],0,0,0); \
    acc[1] = __builtin_amdgcn_mfma_f32_16x16x32_f16(AA, WF[2], acc[1],0,0,0); \
    acc[1] = __builtin_amdgcn_mfma_f32_16x16x32_f16(AB, WF[3], acc[1],0,0,0); \
    acc[2] = __builtin_amdgcn_mfma_f32_16x16x32_f16(AA, WF[4], acc[2],0,0,0); \
    acc[2] = __builtin_amdgcn_mfma_f32_16x16x32_f16(AB, WF[5], acc[2],0,0,0); \
    acc[3] = __builtin_amdgcn_mfma_f32_16x16x32_f16(AA, WF[6], acc[3],0,0,0); \
    acc[3] = __builtin_amdgcn_mfma_f32_16x16x32_f16(AB, WF[7], acc[3],0,0,0); \
    __builtin_amdgcn_s_setprio(0);                                            \
  } while(0)

    // ---- prologue: GA(0) in flight; meta(1) ready ----
    float wA00, wA01, wA10, wA11; const _Float16 *pA0, *pA1, *pA2, *pA3;
    float wB00, wB01, wB10, wB11; const _Float16 *pB0, *pB1, *pB2, *pB3;
    h8 GA[8], GB[8];

    DCN_META(0, wA00,wA01,wA10,wA11, pA0,pA1,pA2,pA3);
    DCN_GATHER(GA, pA0,pA1,pA2,pA3);
    DCN_META(1, wB00,wB01,wB10,wB11, pB0,pB1,pB2,pB3);

#pragma unroll 1
    for (int kp = 0; kp < 4; kp++) {
        const int ke = kp*2;
        // ---- tap ke (even): GA holds data; W from LDS ----
        DCN_GATHER(GB, pB0,pB1,pB2,pB3);                // tap ke+1 in flight
        h8 WE[8]; DCN_WREAD(ke, WE);                    // lgkm, off vmcnt path
        float nA00,nA01,nA10,nA11; const _Float16 *qA0,*qA1,*qA2,*qA3;
        DCN_META(ke+2, nA00,nA01,nA10,nA11, qA0,qA1,qA2,qA3);   // ke+2 <= 8
        h8 aA, aB; DCN_COMBINE(GA, wA00,wA01,wA10,wA11, aA, aB);
        DCN_MFMA(WE, aA, aB);
        wA00=nA00; wA01=nA01; wA10=nA10; wA11=nA11;
        pA0=qA0; pA1=qA1; pA2=qA2; pA3=qA3;
        DCN_GATHER(GA, pA0,pA1,pA2,pA3);                // tap ke+2 in flight

        // ---- tap ke+1 (odd): GB holds data; W from LDS ----
        h8 WO[8]; DCN_WREAD(ke+1, WO);
        float nB00,nB01,nB10,nB11; const _Float16 *qB0,*qB1,*qB2,*qB3;
        if (kp < 3) {
            DCN_META(ke+3, nB00,nB01,nB10,nB11, qB0,qB1,qB2,qB3);
        } else {
            nB00=wB00; nB01=wB01; nB10=wB10; nB11=wB11;
            qB0=pB0; qB1=pB1; qB2=pB2; qB3=pB3;
        }
        h8 cA, cB; DCN_COMBINE(GB, wB00,wB01,wB10,wB11, cA, cB);
        DCN_MFMA(WO, cA, cB);
        wB00=nB00; wB01=nB01; wB10=nB10; wB11=nB11;
        pB0=qB0; pB1=qB1; pB2=qB2; pB3=qB3;
    }

    // ---- tap 8 (in GA / wA) ----
    {
        h8 WE[8]; DCN_WREAD(8, WE);
        h8 aA, aB; DCN_COMBINE(GA, wA00,wA01,wA10,wA11, aA, aB);
        DCN_MFMA(WE, aA, aB);
    }

    // ---- epilogue: D row px = wv*16 + fq*4 + reg, col o = j*16 + fr ----
    const int bo = px0 / HW_, po = px0 % HW_;
#pragma unroll
    for (int j = 0; j < 4; j++) {
        int o = j*16 + fr;
        float bv = bias[o];
        f4 r = { acc[j][0] + bv, acc[j][1] + bv, acc[j][2] + bv, acc[j][3] + bv };
        *reinterpret_cast<f4*>(&out[((size_t)(bo*64 + o))*HW_ + po + wv*16 + fq*4]) = r;
    }
}

// ---------------------------------------------------------------------------
extern "C" void kernel_launch(void* const* d_in, const int* in_sizes, int n_in,
                              void* d_out, int out_size, void* d_ws, size_t ws_size,
                              hipStream_t stream)
{
    const float* x   = (const float*)d_in[0];
    const float* wt  = (const float*)d_in[1];
    const float* bs  = (const float*)d_in[2];
    const float* cmw = (const float*)d_in[3];
    const float* cmb = (const float*)d_in[4];
    float* out = (float*)d_out;

    _Float16* xsh  = (_Float16*)d_ws;                       // NPIX_*72 fp16
    _Float16* wlin = xsh + (size_t)NPIX_ * XC_;             // 9*4096 fp16
    _Float16* cwL  = wlin + 9*4096;                         // 21*1024 fp16

    prep_kernel <<<228, 256, 0, stream>>>(wt, cmw, wlin, cwL);
    xpose_kernel<<<NPIX_/128, 128, 0, stream>>>(x, xsh);
    sim_kernel  <<<NPIX_/64,  256, 0, stream>>>(xsh);
    cmdcn_kernel<<<NPIX_/64,  256, 0, stream>>>(xsh, cwL, cmb, wlin, bs, out);
}

// Round 23
// 66.035 us; speedup vs baseline: 1.2314x; 1.1172x over previous
//
#include <hip/hip_runtime.h>
#include <math.h>

#define B_    4
#define CIN_  64
#define COUT_ 64
#define H_    128
#define W_    160
#define HW_   (H_*W_)
#define NPIX_ (B_*HW_)      // 81920
#define XC_   72            // xsh channel stride: x(64) + sim(8), fp16
#define EPS_  1e-8f
#define NCH_  21            // cm K-chunks: ceil(648/32)

typedef float     f4    __attribute__((ext_vector_type(4)));
typedef float     f32x4 __attribute__((ext_vector_type(4)));
typedef _Float16  h8    __attribute__((ext_vector_type(8)));
typedef _Float16  h4    __attribute__((ext_vector_type(4)));

// ---------------------------------------------------------------------------
// xpose (+merged prep): NCHW f32 x -> fp16 NHWC xsh[px][0..63]; 256 thr/block
// (c-range split across thread-halves). Each thread additionally does <=1
// element of the weight prep (independent work; deletes the prep launch):
//  wlin[k][j][s][lane][8] fp16 (9*4096): dcn W-fragments pre-linearized.
//  cwL[CH][s][lane][8] fp16 (21*1024): cm W-fragments, same linearization.
// ---------------------------------------------------------------------------
__global__ __launch_bounds__(256) void xpose_kernel(const float* __restrict__ x,
                                                    _Float16* __restrict__ xsh,
                                                    const float* __restrict__ wt,
                                                    const float* __restrict__ cmw,
                                                    _Float16* __restrict__ wlin,
                                                    _Float16* __restrict__ cwL)
{
    __shared__ float l[128][65];
    const int t = threadIdx.x;
    const int px0 = blockIdx.x * 128;
    const int b = px0 / HW_, p0 = px0 % HW_;
    const int half = t >> 7, tl = t & 127;

    // ---- load: 2 thread-halves each cover 32 channels of 128 px ----
#pragma unroll 8
    for (int c = 0; c < 32; c++)
        l[tl][half*32 + c] = x[((size_t)(b*64 + half*32 + c))*HW_ + p0 + tl];

    // ---- merged prep (independent of LDS; issued before the barrier) ----
    {
        int i = blockIdx.x * 256 + t;
        if (i < 9*4096) {
            int k = i >> 12, r = i & 4095;
            int j = r >> 10, s = (r >> 9) & 1, lane = (r >> 3) & 63, e = i & 7;
            int o = j*16 + (lane & 15);
            int c = s*32 + ((lane >> 4) << 3) + e;
            wlin[i] = (_Float16)wt[(o*64 + c)*9 + k];
        }
        int jj = i - 9*4096;
        if (jj >= 0 && jj < NCH_*1024) {
            int CH = jj >> 10, s = (jj >> 9) & 1, lane = (jj >> 3) & 63, e = jj & 7;
            int o  = s*16 + (lane & 15);
            int kk = ((lane >> 4) << 3) + e;
            int k  = CH*32 + kk;
            _Float16 v = (_Float16)0.f;
            if (o < 27 && k < 648) {
                int tap = k / 72, ch = k - (k/72)*72;
                v = (_Float16)cmw[((size_t)o*72 + ch)*9 + tap];
            }
            cwL[jj] = v;
        }
    }
    __syncthreads();

    // ---- write: 2048 (px, c4) tasks over 8 reps x 256 thr ----
#pragma unroll
    for (int rep = 0; rep < 8; rep++) {
        int task = rep*256 + t;
        int pxl  = task >> 4;
        int c4   = (task & 15) * 4;
        h4 v = { (_Float16)l[pxl][c4],   (_Float16)l[pxl][c4+1],
                 (_Float16)l[pxl][c4+2], (_Float16)l[pxl][c4+3] };
        *reinterpret_cast<h4*>(&xsh[(size_t)(px0+pxl)*XC_ + c4]) = v;
    }
}

// ---------------------------------------------------------------------------
// sim: 4 threads/pixel (16-ch quarters), 2-level shfl_xor combine.
// 256-thread blocks, 64 px each, grid 1280. Writes xsh[px][64..71].
// ---------------------------------------------------------------------------
__global__ __launch_bounds__(256, 4) void sim_kernel(_Float16* __restrict__ xsh)
{
    const int t = threadIdx.x;
    const int wg = blockIdx.x;
    const int sw = (wg & 7) * 160 + (wg >> 3);              // XCD-contiguous
    const int px = sw * 64 + (t >> 2);
    const int q = t & 3;
    const int w = px % W_, hh = (px / W_) % H_, b = px / HW_;

    const _Float16* cen = xsh + (size_t)px * XC_ + q*16;
    float cv[16]; float ncc = 0.f;
#pragma unroll
    for (int s = 0; s < 2; s++) {
        h8 cb = *reinterpret_cast<const h8*>(cen + s*8);
#pragma unroll
        for (int j = 0; j < 8; j++) {
            float v = (float)cb[j];
            cv[s*8+j] = v;
            ncc = fmaf(v, v, ncc);
        }
    }

    const int kyA[8] = {-1,-1,-1, 0, 0, 1, 1, 1};
    const int kxA[8] = {-1, 0, 1,-1, 1,-1, 0, 1};
    float dot[8], nn[8];
#pragma unroll
    for (int n = 0; n < 8; n++) {
        int hn = hh + kyA[n], wn = w + kxA[n];
        bool v = (hn >= 0) & (hn < H_) & (wn >= 0) & (wn < W_);
        float msk = v ? 1.f : 0.f;
        const _Float16* nb = xsh + (size_t)(b*HW_ + min(max(hn,0),H_-1)*W_ + min(max(wn,0),W_-1))*XC_ + q*16;
        float d = 0.f, s2 = 0.f;
#pragma unroll
        for (int s = 0; s < 2; s++) {
            h8 qb = *reinterpret_cast<const h8*>(nb + s*8);
#pragma unroll
            for (int j = 0; j < 8; j++) {
                float vv = (float)qb[j] * msk;
                d  = fmaf(cv[s*8+j], vv, d);
                s2 = fmaf(vv, vv, s2);
            }
        }
        dot[n] = d; nn[n] = s2;
    }
    ncc += __shfl_xor(ncc, 1); ncc += __shfl_xor(ncc, 2);
    const float ncr = 1.f / fmaxf(sqrtf(ncc), EPS_);
    float res[8];
#pragma unroll
    for (int n = 0; n < 8; n++) {
        float dt = dot[n]; dt += __shfl_xor(dt, 1); dt += __shfl_xor(dt, 2);
        float s2 = nn[n];  s2 += __shfl_xor(s2, 1); s2 += __shfl_xor(s2, 2);
        res[n] = dt * ncr / fmaxf(sqrtf(s2), EPS_);
    }
    if (q < 2) {
        h4 r = { (_Float16)res[q*4],   (_Float16)res[q*4+1],
                 (_Float16)res[q*4+2], (_Float16)res[q*4+3] };
        *reinterpret_cast<h4*>(xsh + (size_t)px * XC_ + 64 + q*4) = r;
    }
}

// ---------------------------------------------------------------------------
// cmdcn: FUSED cm + dcn, fp16. Block = 64 px, 4 waves, grid 1280.
// R22 shape verbatim (measured 47.5us): all 9 dcn W taps (72KB) in LDS,
// G ping-pong, packed-fp16 combine, s_setprio around MFMA clusters.
// ---------------------------------------------------------------------------
__global__ __launch_bounds__(256, 2) void cmdcn_kernel(const _Float16* __restrict__ xsh,
                                                       const _Float16* __restrict__ cwL,
                                                       const float* __restrict__ cmb,
                                                       const _Float16* __restrict__ wlin,
                                                       const float* __restrict__ bias,
                                                       float* __restrict__ out)
{
    __shared__ float om_l[64][29];                          // 7.4 KB
    __shared__ __align__(16) _Float16 WLds[9*4096];         // 72 KB

    const int t  = threadIdx.x;
    const int wg = blockIdx.x;
    const int sw = (wg & 7) * 160 + (wg >> 3);              // XCD-contiguous
    const int px0 = sw * 64;
    const int lane = t & 63, wv = t >> 6;
    const int fr = lane & 15, fq = lane >> 4;

    // ---- stage all 9 W taps to LDS (4608 chunks = 18 rounds x 256 thr) ----
#pragma unroll 3
    for (int r = 0; r < 18; r++) {
        int cb = r*256 + t;
        *reinterpret_cast<h8*>(&WLds[cb*8]) =
            *reinterpret_cast<const h8*>(wlin + cb*8);
    }

    const int pxs = px0 + wv*16 + fr;
    const int wsx = pxs % W_, hs = (pxs / W_) % H_, bs = pxs / HW_;
    const size_t xrow = (size_t)bs * HW_;

    // ================= phase 1: cm (2-deep ping-pong) =================
    {
        f32x4 acc[2];
        acc[0] = (f32x4){0.f,0.f,0.f,0.f};
        acc[1] = (f32x4){0.f,0.f,0.f,0.f};

#define CM_ISSUE_G(CH, G8, MSK) do {                                          \
    int k0_ = (CH)*32 + fq*8;                                                 \
    int tap_ = (k0_ * 911) >> 16;                                             \
    bool valid_ = (tap_ < 9);                                                 \
    tap_ = min(tap_, 8);                                                      \
    int ch_ = min(max(k0_ - tap_*72, 0), 64);                                 \
    int t3_ = (tap_ * 11) >> 5;                                               \
    int hy_ = hs + t3_ - 1, wx_ = wsx + (tap_ - t3_*3) - 1;                   \
    bool v_ = (hy_ >= 0) & (hy_ < H_) & (wx_ >= 0) & (wx_ < W_);              \
    MSK = v_ & valid_;                                                        \
    const _Float16* src_ = xsh + (size_t)(xrow + min(max(hy_,0),H_-1)*W_      \
                                          + min(max(wx_,0),W_-1))*XC_ + ch_;  \
    G8 = *reinterpret_cast<const h8*>(src_);                                  \
  } while(0)

#define CM_ISSUE_W(CH, WF) do {                                               \
    const _Float16* wp_ = cwL + (CH)*1024 + lane*8;                           \
    WF[0] = *reinterpret_cast<const h8*>(wp_);                                \
    WF[1] = *reinterpret_cast<const h8*>(wp_ + 512);                          \
  } while(0)

#define CM_MFMA(G8, MSK, WF) do {                                             \
    h8 zero8_ = {(_Float16)0.f,(_Float16)0.f,(_Float16)0.f,(_Float16)0.f,     \
                 (_Float16)0.f,(_Float16)0.f,(_Float16)0.f,(_Float16)0.f};    \
    h8 AF_ = (MSK) ? (G8) : zero8_;                                           \
    __builtin_amdgcn_s_setprio(1);                                            \
    acc[0] = __builtin_amdgcn_mfma_f32_16x16x32_f16(AF_, WF[0], acc[0],0,0,0);\
    acc[1] = __builtin_amdgcn_mfma_f32_16x16x32_f16(AF_, WF[1], acc[1],0,0,0);\
    __builtin_amdgcn_s_setprio(0);                                            \
  } while(0)

        h8 GAc, GBc; h8 WFA[2], WFB[2]; bool mskA, mskB;
        CM_ISSUE_G(0, GAc, mskA); CM_ISSUE_W(0, WFA);
        CM_ISSUE_G(1, GBc, mskB); CM_ISSUE_W(1, WFB);

#pragma unroll 1
        for (int cp = 0; cp < 10; cp++) {
            const int cce = cp*2;
            {   // even chunk cce (GA)
                h8 G = GAc; bool m = mskA; h8 W0 = WFA[0], W1 = WFA[1];
                if (cce + 2 < NCH_) { CM_ISSUE_G(cce+2, GAc, mskA); CM_ISSUE_W(cce+2, WFA); }
                h8 zero8_ = {(_Float16)0.f,(_Float16)0.f,(_Float16)0.f,(_Float16)0.f,
                             (_Float16)0.f,(_Float16)0.f,(_Float16)0.f,(_Float16)0.f};
                h8 AF_ = m ? G : zero8_;
                __builtin_amdgcn_s_setprio(1);
                acc[0] = __builtin_amdgcn_mfma_f32_16x16x32_f16(AF_, W0, acc[0],0,0,0);
                acc[1] = __builtin_amdgcn_mfma_f32_16x16x32_f16(AF_, W1, acc[1],0,0,0);
                __builtin_amdgcn_s_setprio(0);
            }
            {   // odd chunk cce+1 (GB)
                h8 G = GBc; bool m = mskB; h8 W0 = WFB[0], W1 = WFB[1];
                if (cce + 3 < NCH_) { CM_ISSUE_G(cce+3, GBc, mskB); CM_ISSUE_W(cce+3, WFB); }
                h8 zero8_ = {(_Float16)0.f,(_Float16)0.f,(_Float16)0.f,(_Float16)0.f,
                             (_Float16)0.f,(_Float16)0.f,(_Float16)0.f,(_Float16)0.f};
                h8 AF_ = m ? G : zero8_;
                __builtin_amdgcn_s_setprio(1);
                acc[0] = __builtin_amdgcn_mfma_f32_16x16x32_f16(AF_, W0, acc[0],0,0,0);
                acc[1] = __builtin_amdgcn_mfma_f32_16x16x32_f16(AF_, W1, acc[1],0,0,0);
                __builtin_amdgcn_s_setprio(0);
            }
        }
        CM_MFMA(GAc, mskA, WFA);                            // tail chunk 20

        // epilogue -> LDS: row px = wv*16 + fq*4 + r, col o = j*16 + fr
        const int rl = wv*16 + fq*4;
#pragma unroll
        for (int j = 0; j < 2; j++) {
            int o = j*16 + fr;
            if (o < 27) {
                float bv = cmb[o];
#pragma unroll
                for (int r = 0; r < 4; r++)
                    om_l[rl + r][o] = acc[j][r] + bv;
            }
        }
    }
    __syncthreads();                                        // covers W staging too

    // ================= phase 2: dcn (G ping-pong; W from LDS) =============
    const int ce = fq * 8;
    const int rp = wv*16 + fr;                              // this lane's px row
    const int lb = lane*8;

    f32x4 acc[4];
#pragma unroll
    for (int j = 0; j < 4; j++) acc[j] = (f32x4){0.f,0.f,0.f,0.f};

#define DCN_META(KK, W00, W01, W10, W11, P0, P1, P2, P3) do {                 \
    float dy_ = om_l[rp][2*(KK)], dx_ = om_l[rp][2*(KK)+1];                   \
    float mz_ = om_l[rp][18+(KK)];                                            \
    float m_  = 1.f / (1.f + __expf(-mz_));                                   \
    float py_ = (float)(hs + (KK)/3 - 1) + dy_;                               \
    float px_ = (float)(wsx + (KK)%3 - 1) + dx_;                              \
    float y0f_ = floorf(py_), x0f_ = floorf(px_);                             \
    int   y0_ = (int)y0f_,   x0_ = (int)x0f_;                                 \
    float wy_ = py_ - y0f_,  wx_ = px_ - x0f_;                                \
    bool vy0_ = (y0_ >= 0)  & (y0_ < H_);                                     \
    bool vy1_ = (y0_ >= -1) & (y0_ < H_ - 1);                                 \
    bool vx0_ = (x0_ >= 0)  & (x0_ < W_);                                     \
    bool vx1_ = (x0_ >= -1) & (x0_ < W_ - 1);                                 \
    W00 = (1.f-wy_)*(1.f-wx_)*m_*((vy0_&vx0_)?1.f:0.f);                       \
    W01 = (1.f-wy_)*wx_      *m_*((vy0_&vx1_)?1.f:0.f);                       \
    W10 = wy_*(1.f-wx_)      *m_*((vy1_&vx0_)?1.f:0.f);                       \
    W11 = wy_*wx_            *m_*((vy1_&vx1_)?1.f:0.f);                       \
    int y0c_ = min(max(y0_,   0), H_-1), y1c_ = min(max(y0_+1, 0), H_-1);     \
    int x0c_ = min(max(x0_,   0), W_-1), x1c_ = min(max(x0_+1, 0), W_-1);     \
    P0 = xsh + (size_t)(xrow + y0c_*W_ + x0c_)*XC_ + ce;                      \
    P1 = xsh + (size_t)(xrow + y0c_*W_ + x1c_)*XC_ + ce;                      \
    P2 = xsh + (size_t)(xrow + y1c_*W_ + x0c_)*XC_ + ce;                      \
    P3 = xsh + (size_t)(xrow + y1c_*W_ + x1c_)*XC_ + ce;                      \
  } while(0)

#define DCN_GATHER(G, P0, P1, P2, P3) do {                                    \
    G[0] = *reinterpret_cast<const h8*>(P0);                                  \
    G[1] = *reinterpret_cast<const h8*>(P0 + 32);                             \
    G[2] = *reinterpret_cast<const h8*>(P1);                                  \
    G[3] = *reinterpret_cast<const h8*>(P1 + 32);                             \
    G[4] = *reinterpret_cast<const h8*>(P2);                                  \
    G[5] = *reinterpret_cast<const h8*>(P2 + 32);                             \
    G[6] = *reinterpret_cast<const h8*>(P3);                                  \
    G[7] = *reinterpret_cast<const h8*>(P3 + 32);                             \
  } while(0)

#define DCN_WREAD(KK, WF) do {                                                \
    const _Float16* wp_ = &WLds[(KK)*4096 + lb];                              \
    WF[0] = *reinterpret_cast<const h8*>(wp_);                                \
    WF[1] = *reinterpret_cast<const h8*>(wp_ + 512);                          \
    WF[2] = *reinterpret_cast<const h8*>(wp_ + 1024);                         \
    WF[3] = *reinterpret_cast<const h8*>(wp_ + 1536);                         \
    WF[4] = *reinterpret_cast<const h8*>(wp_ + 2048);                         \
    WF[5] = *reinterpret_cast<const h8*>(wp_ + 2560);                         \
    WF[6] = *reinterpret_cast<const h8*>(wp_ + 3072);                         \
    WF[7] = *reinterpret_cast<const h8*>(wp_ + 3584);                         \
  } while(0)

#define DCN_COMBINE(G, W00, W01, W10, W11, AA, AB) do {                       \
    _Float16 h00 = (_Float16)(W00), h01 = (_Float16)(W01);                    \
    _Float16 h10 = (_Float16)(W10), h11 = (_Float16)(W11);                    \
    h8 v00 = {h00,h00,h00,h00,h00,h00,h00,h00};                               \
    h8 v01 = {h01,h01,h01,h01,h01,h01,h01,h01};                               \
    h8 v10 = {h10,h10,h10,h10,h10,h10,h10,h10};                               \
    h8 v11 = {h11,h11,h11,h11,h11,h11,h11,h11};                               \
    AA = v00*G[0] + v01*G[2] + v10*G[4] + v11*G[6];                           \
    AB = v00*G[1] + v01*G[3] + v10*G[5] + v11*G[7];                           \
  } while(0)

#define DCN_MFMA(WF, AA, AB) do {                                             \
    __builtin_amdgcn_s_setprio(1);                                            \
    acc[0] = __builtin_amdgcn_mfma_f32_16x16x32_f16(AA, WF[0], acc[0],0,0,0); \
    acc[0] = __builtin_amdgcn_mfma_f32_16x16x32_f16(AB, WF[1], acc[0],0,0,0); \
    acc[1] = __builtin_amdgcn_mfma_f32_16x16x32_f16(AA, WF[2], acc[1],0,0,0); \
    acc[1] = __builtin_amdgcn_mfma_f32_16x16x32_f16(AB, WF[3], acc[1],0,0,0); \
    acc[2] = __builtin_amdgcn_mfma_f32_16x16x32_f16(AA, WF[4], acc[2],0,0,0); \
    acc[2] = __builtin_amdgcn_mfma_f32_16x16x32_f16(AB, WF[5], acc[2],0,0,0); \
    acc[3] = __builtin_amdgcn_mfma_f32_16x16x32_f16(AA, WF[6], acc[3],0,0,0); \
    acc[3] = __builtin_amdgcn_mfma_f32_16x16x32_f16(AB, WF[7], acc[3],0,0,0); \
    __builtin_amdgcn_s_setprio(0);                                            \
  } while(0)

    // ---- prologue: GA(0) in flight; meta(1) ready ----
    float wA00, wA01, wA10, wA11; const _Float16 *pA0, *pA1, *pA2, *pA3;
    float wB00, wB01, wB10, wB11; const _Float16 *pB0, *pB1, *pB2, *pB3;
    h8 GA[8], GB[8];

    DCN_META(0, wA00,wA01,wA10,wA11, pA0,pA1,pA2,pA3);
    DCN_GATHER(GA, pA0,pA1,pA2,pA3);
    DCN_META(1, wB00,wB01,wB10,wB11, pB0,pB1,pB2,pB3);

#pragma unroll 1
    for (int kp = 0; kp < 4; kp++) {
        const int ke = kp*2;
        // ---- tap ke (even): GA holds data; W from LDS ----
        DCN_GATHER(GB, pB0,pB1,pB2,pB3);                // tap ke+1 in flight
        h8 WE[8]; DCN_WREAD(ke, WE);                    // lgkm, off vmcnt path
        float nA00,nA01,nA10,nA11; const _Float16 *qA0,*qA1,*qA2,*qA3;
        DCN_META(ke+2, nA00,nA01,nA10,nA11, qA0,qA1,qA2,qA3);   // ke+2 <= 8
        h8 aA, aB; DCN_COMBINE(GA, wA00,wA01,wA10,wA11, aA, aB);
        DCN_MFMA(WE, aA, aB);
        wA00=nA00; wA01=nA01; wA10=nA10; wA11=nA11;
        pA0=qA0; pA1=qA1; pA2=qA2; pA3=qA3;
        DCN_GATHER(GA, pA0,pA1,pA2,pA3);                // tap ke+2 in flight

        // ---- tap ke+1 (odd): GB holds data; W from LDS ----
        h8 WO[8]; DCN_WREAD(ke+1, WO);
        float nB00,nB01,nB10,nB11; const _Float16 *qB0,*qB1,*qB2,*qB3;
        if (kp < 3) {
            DCN_META(ke+3, nB00,nB01,nB10,nB11, qB0,qB1,qB2,qB3);
        } else {
            nB00=wB00; nB01=wB01; nB10=wB10; nB11=wB11;
            qB0=pB0; qB1=pB1; qB2=pB2; qB3=pB3;
        }
        h8 cA, cB; DCN_COMBINE(GB, wB00,wB01,wB10,wB11, cA, cB);
        DCN_MFMA(WO, cA, cB);
        wB00=nB00; wB01=nB01; wB10=nB10; wB11=nB11;
        pB0=qB0; pB1=qB1; pB2=qB2; pB3=qB3;
    }

    // ---- tap 8 (in GA / wA) ----
    {
        h8 WE[8]; DCN_WREAD(8, WE);
        h8 aA, aB; DCN_COMBINE(GA, wA00,wA01,wA10,wA11, aA, aB);
        DCN_MFMA(WE, aA, aB);
    }

    // ---- epilogue: D row px = wv*16 + fq*4 + reg, col o = j*16 + fr ----
    const int bo = px0 / HW_, po = px0 % HW_;
#pragma unroll
    for (int j = 0; j < 4; j++) {
        int o = j*16 + fr;
        float bv = bias[o];
        f4 r = { acc[j][0] + bv, acc[j][1] + bv, acc[j][2] + bv, acc[j][3] + bv };
        *reinterpret_cast<f4*>(&out[((size_t)(bo*64 + o))*HW_ + po + wv*16 + fq*4]) = r;
    }
}

// ---------------------------------------------------------------------------
extern "C" void kernel_launch(void* const* d_in, const int* in_sizes, int n_in,
                              void* d_out, int out_size, void* d_ws, size_t ws_size,
                              hipStream_t stream)
{
    const float* x   = (const float*)d_in[0];
    const float* wt  = (const float*)d_in[1];
    const float* bs  = (const float*)d_in[2];
    const float* cmw = (const float*)d_in[3];
    const float* cmb = (const float*)d_in[4];
    float* out = (float*)d_out;

    _Float16* xsh  = (_Float16*)d_ws;                       // NPIX_*72 fp16
    _Float16* wlin = xsh + (size_t)NPIX_ * XC_;             // 9*4096 fp16
    _Float16* cwL  = wlin + 9*4096;                         // 21*1024 fp16

    xpose_kernel<<<NPIX_/128, 256, 0, stream>>>(x, xsh, wt, cmw, wlin, cwL);
    sim_kernel  <<<NPIX_/64,  256, 0, stream>>>(xsh);
    cmdcn_kernel<<<NPIX_/64,  256, 0, stream>>>(xsh, cwL, cmb, wlin, bs, out);
}